// Round 2
// baseline (129.961 us; speedup 1.0000x reference)
//
#include <hip/hip_runtime.h>
#include <math.h>

#define THREADS 256
#define NWAVES (THREADS / 64)
#define HIST_BINS 4096
#define CAP 4096

__device__ __forceinline__ unsigned orderKey(float f) {
    unsigned u = __float_as_uint(f);
    return (u & 0x80000000u) ? ~u : (u | 0x80000000u);
}

// One block per candidate token. Computes top_prob (= max softmax prob after
// top-k + top-p masking) and top_token (argmax) exactly per the reference.
__global__ __launch_bounds__(THREADS) void token_kernel(
    const float* __restrict__ logits,
    const int* __restrict__ rel_idx,
    const int* __restrict__ cu_filtered,
    const int* __restrict__ cu_q,
    const float* __restrict__ temps,
    const int* __restrict__ topk_p,
    const float* __restrict__ topp_p,
    int bsz, long long logits_n,
    float* __restrict__ ws_prob,
    int* __restrict__ ws_token)
{
    __shared__ int s_hist[HIST_BINS];    // reused as sorted[] (float) later
    __shared__ float s_coll[CAP];        // collected candidates, reused as e[]
    __shared__ float s_wmax[NWAVES];
    __shared__ int s_widx[NWAVES];
    __shared__ int s_b, s_vocab, s_kk, s_n, s_m, s_amax;
    __shared__ unsigned s_T;
    __shared__ float s_M;

    const int t = blockIdx.x;
    const int tid = threadIdx.x;

    if (tid == 0) {
        int b = 0;
        while (t >= cu_filtered[b + 1]) b++;
        s_b = b;
        int nrows = cu_q[bsz];
        int vocab = (int)(logits_n / (long long)nrows);
        s_vocab = vocab;
        int kk = topk_p[0];
        if (kk > vocab) kk = vocab;
        s_kk = kk;
        s_n = 0;
    }
    for (int i = tid; i < HIST_BINS; i += THREADS) s_hist[i] = 0;
    __syncthreads();

    const int b = s_b;
    const int vocab = s_vocab;
    const float T = temps[t];
    const long long grow = (long long)cu_q[b] + (long long)rel_idx[t];
    const float* row = logits + grow * (long long)vocab;
    const float4* row4 = (const float4*)row;
    const int nv4 = vocab >> 2;

    // ---- pass 1: max/argmax (first-index tie) + 12-bit key histogram ----
    float bestV = -INFINITY;
    int bestI = 0x7fffffff;
    for (int i = tid; i < nv4; i += THREADS) {
        float4 v = row4[i];
        int base = i << 2;
        float a0 = v.x / T, a1 = v.y / T, a2 = v.z / T, a3 = v.w / T;
        atomicAdd(&s_hist[orderKey(a0) >> 20], 1);
        atomicAdd(&s_hist[orderKey(a1) >> 20], 1);
        atomicAdd(&s_hist[orderKey(a2) >> 20], 1);
        atomicAdd(&s_hist[orderKey(a3) >> 20], 1);
        if (a0 > bestV || (a0 == bestV && base < bestI)) { bestV = a0; bestI = base; }
        if (a1 > bestV || (a1 == bestV && base + 1 < bestI)) { bestV = a1; bestI = base + 1; }
        if (a2 > bestV || (a2 == bestV && base + 2 < bestI)) { bestV = a2; bestI = base + 2; }
        if (a3 > bestV || (a3 == bestV && base + 3 < bestI)) { bestV = a3; bestI = base + 3; }
    }
    for (int i = (nv4 << 2) + tid; i < vocab; i += THREADS) {
        float a = row[i] / T;
        atomicAdd(&s_hist[orderKey(a) >> 20], 1);
        if (a > bestV || (a == bestV && i < bestI)) { bestV = a; bestI = i; }
    }
    // wave reduce (64 lanes)
    for (int off = 32; off > 0; off >>= 1) {
        float ov = __shfl_down(bestV, off);
        int oi = __shfl_down(bestI, off);
        if (ov > bestV || (ov == bestV && oi < bestI)) { bestV = ov; bestI = oi; }
    }
    if ((tid & 63) == 0) { s_wmax[tid >> 6] = bestV; s_widx[tid >> 6] = bestI; }
    __syncthreads();
    if (tid == 0) {
        float M = s_wmax[0]; int ai = s_widx[0];
        for (int w = 1; w < NWAVES; ++w) {
            if (s_wmax[w] > M || (s_wmax[w] == M && s_widx[w] < ai)) { M = s_wmax[w]; ai = s_widx[w]; }
        }
        s_M = M; s_amax = ai;
        // find threshold bin: smallest key-bin B with count(key >= B<<20) >= kk
        int B = (int)(orderKey(M) >> 20);
        int cum = 0;
        while (true) {
            cum += s_hist[B];
            if (cum >= s_kk || B == 0) break;
            --B;
        }
        s_T = ((unsigned)B) << 20;
    }
    __syncthreads();

    // ---- pass 2: collect values with key >= T (cache-resident re-read) ----
    const unsigned Tkey = s_T;
    for (int i = tid; i < nv4; i += THREADS) {
        float4 v = row4[i];
        float a0 = v.x / T, a1 = v.y / T, a2 = v.z / T, a3 = v.w / T;
        if (orderKey(a0) >= Tkey) { int p = atomicAdd(&s_n, 1); if (p < CAP) s_coll[p] = a0; }
        if (orderKey(a1) >= Tkey) { int p = atomicAdd(&s_n, 1); if (p < CAP) s_coll[p] = a1; }
        if (orderKey(a2) >= Tkey) { int p = atomicAdd(&s_n, 1); if (p < CAP) s_coll[p] = a2; }
        if (orderKey(a3) >= Tkey) { int p = atomicAdd(&s_n, 1); if (p < CAP) s_coll[p] = a3; }
    }
    for (int i = (nv4 << 2) + tid; i < vocab; i += THREADS) {
        float a = row[i] / T;
        if (orderKey(a) >= Tkey) { int p = atomicAdd(&s_n, 1); if (p < CAP) s_coll[p] = a; }
    }
    __syncthreads();
    int n = s_n; if (n > CAP) n = CAP;

    // ---- rank-sort collected values descending into sorted[] ----
    float* sorted = (float*)s_hist;
    for (int i = tid; i < n; i += THREADS) {
        float v = s_coll[i];
        int r = 0;
        for (int j = 0; j < n; ++j) {
            float w = s_coll[j];
            r += (w > v) || (w == v && j < i);
        }
        sorted[r] = v;
    }
    __syncthreads();
    if (tid == 0) {
        int kk = s_kk;
        float thr = sorted[kk - 1];
        int m = kk;
        while (m < n && sorted[m] >= thr) ++m;   // include ties at thr_k
        s_m = m;
    }
    __syncthreads();
    const int m = s_m;
    const float M = s_M;
    for (int i = tid; i < m; i += THREADS) s_coll[i] = expf(sorted[i] - M);
    __syncthreads();
    if (tid == 0) {
        float Z1 = 0.f;
        for (int i = 0; i < m; ++i) Z1 += s_coll[i];
        const float topp = topp_p[0];
        int j = m - 1;
        float c = 0.f;
        for (int i = 0; i < m; ++i) {
            float p = s_coll[i] / Z1;
            c += p;
            if (c > topp) { j = i; break; }
        }
        float Z2 = 0.f;
        for (int i = 0; i <= j; ++i) Z2 += s_coll[i];
        ws_prob[t] = 1.0f / Z2;
        ws_token[t] = s_amax;
    }
}

// One wave per batch: stable sort by score desc, filter, write int32 outputs.
__global__ __launch_bounds__(64) void finalize_kernel(
    const float* __restrict__ ws_prob,
    const int* __restrict__ ws_token,
    const int* __restrict__ rel_idx,
    const int* __restrict__ boff,
    const int* __restrict__ cu_filtered,
    const int* __restrict__ num_transfer,
    const float* __restrict__ thresholds,
    int bsz, int L,
    int* __restrict__ out)
{
    const int bq = blockIdx.x;
    const int l = threadIdx.x;
    const int start = cu_filtered[bq];
    int cnt = cu_filtered[bq + 1] - start;
    if (cnt > L) cnt = L;

    __shared__ float ss[64]; __shared__ int stk[64]; __shared__ int sp[64];
    __shared__ float ss2[64]; __shared__ int stk2[64]; __shared__ int sp2[64];

    float score = -INFINITY; int tok = 0; int pos = 0;
    if (l < L) {
        if (l < cnt) {
            int t = start + l;
            score = ws_prob[t];
            tok = ws_token[t];
            pos = rel_idx[t] + boff[bq];
        }
        ss[l] = score; stk[l] = tok; sp[l] = pos;
    }
    __syncthreads();
    if (l < L) {
        int r = 0;
        for (int j = 0; j < L; ++j) {
            float w = ss[j];
            r += (w > score) || (w == score && j < l);
        }
        ss2[r] = score; stk2[r] = tok; sp2[r] = pos;
    }
    __syncthreads();

    int k = num_transfer[bq]; if (k < 0) k = 0;
    const float thrb = thresholds[bq];
    bool kp = false;
    if (l < L) {
        float s = ss2[l];
        kp = (l < k) && (s >= thrb) && (s > -INFINITY);
        out[bq * L + l] = kp ? sp2[l] : 0;
        out[bsz * L + bq * L + l] = kp ? stk2[l] : -1;
    }
    unsigned long long mask = __ballot(kp);
    if (l == 0) out[2 * bsz * L + bq] = (int)__popcll(mask);
}

extern "C" void kernel_launch(void* const* d_in, const int* in_sizes, int n_in,
                              void* d_out, int out_size, void* d_ws, size_t ws_size,
                              hipStream_t stream) {
    const float* logits   = (const float*)d_in[0];
    const int*   rel      = (const int*)d_in[1];
    const int*   boff     = (const int*)d_in[2];
    const int*   cuf      = (const int*)d_in[3];
    const int*   cuq      = (const int*)d_in[4];
    const float* temps    = (const float*)d_in[5];
    const int*   ntr      = (const int*)d_in[6];
    const float* thr      = (const float*)d_in[7];
    const float* topp     = (const float*)d_in[8];
    const int*   topk     = (const int*)d_in[9];

    const int total = in_sizes[1];
    const int bsz   = in_sizes[6];
    const long long logits_n = (long long)in_sizes[0];
    const int L = (out_size - bsz) / (2 * bsz);   // block_size

    float* ws_prob = (float*)d_ws;
    int*   ws_tok  = (int*)(ws_prob + total);

    token_kernel<<<total, THREADS, 0, stream>>>(
        logits, rel, cuf, cuq, temps, topk, topp, bsz, logits_n, ws_prob, ws_tok);

    finalize_kernel<<<bsz, 64, 0, stream>>>(
        ws_prob, ws_tok, rel, boff, cuf, ntr, thr, bsz, L, (int*)d_out);
}

// Round 3
// 101.842 us; speedup vs baseline: 1.2761x; 1.2761x over previous
//
#include <hip/hip_runtime.h>
#include <math.h>

#define THREADS 256
#define CAP 1024
#define HIST_BINS 4096
#define RAW_THRESH 2.5f

__device__ __forceinline__ unsigned orderKey(float f) {
    unsigned u = __float_as_uint(f);
    return (u & 0x80000000u) ? ~u : (u | 0x80000000u);
}

// One block per candidate token. Single streaming pass over the logits row:
// collect (scaled, idx) for raw >= RAW_THRESH (a superset of top-kk whenever
// count >= kk, verified at runtime; histogram fallback otherwise), then exact
// top-k / top-p / softmax arithmetic on the small collected set.
__global__ __launch_bounds__(THREADS) void token_kernel(
    const float* __restrict__ logits,
    const int* __restrict__ rel_idx,
    const int* __restrict__ cu_filtered,
    const int* __restrict__ cu_q,
    const float* __restrict__ temps,
    const int* __restrict__ topk_p,
    const float* __restrict__ topp_p,
    int bsz, long long logits_n,
    float* __restrict__ ws_prob,
    int* __restrict__ ws_token)
{
    __shared__ float s_vals[CAP];
    __shared__ int   s_idx[CAP];
    __shared__ float s_sorted[CAP];
    __shared__ int   s_hist[HIST_BINS];   // fallback path only
    __shared__ int s_n, s_m, s_amax, s_b, s_vocab, s_kk;
    __shared__ unsigned s_T, s_maxkey;

    const int t = blockIdx.x;
    const int tid = threadIdx.x;

    if (tid == 0) {
        int b = 0;
        while (t >= cu_filtered[b + 1]) b++;
        s_b = b;
        int nrows = cu_q[bsz];
        int vocab = (int)(logits_n / (long long)nrows);
        s_vocab = vocab;
        int kk = topk_p[0];
        if (kk > vocab) kk = vocab;
        s_kk = kk;
        s_n = 0;
    }
    __syncthreads();

    const int vocab = s_vocab;
    const int kk = s_kk;
    const float T = temps[t];
    const long long grow = (long long)cu_q[s_b] + (long long)rel_idx[t];
    const float* row = logits + grow * (long long)vocab;
    const float4* row4 = (const float4*)row;
    const int nv4 = vocab >> 2;

    // ---- single streaming pass: collect raw >= RAW_THRESH ----
    for (int i = tid; i < nv4; i += THREADS) {
        float4 v = row4[i];
        int base = i << 2;
        if (v.x >= RAW_THRESH) { int p = atomicAdd(&s_n, 1); if (p < CAP) { s_vals[p] = v.x / T; s_idx[p] = base; } }
        if (v.y >= RAW_THRESH) { int p = atomicAdd(&s_n, 1); if (p < CAP) { s_vals[p] = v.y / T; s_idx[p] = base + 1; } }
        if (v.z >= RAW_THRESH) { int p = atomicAdd(&s_n, 1); if (p < CAP) { s_vals[p] = v.z / T; s_idx[p] = base + 2; } }
        if (v.w >= RAW_THRESH) { int p = atomicAdd(&s_n, 1); if (p < CAP) { s_vals[p] = v.w / T; s_idx[p] = base + 3; } }
    }
    for (int i = (nv4 << 2) + tid; i < vocab; i += THREADS) {
        float v = row[i];
        if (v >= RAW_THRESH) { int p = atomicAdd(&s_n, 1); if (p < CAP) { s_vals[p] = v / T; s_idx[p] = i; } }
    }
    __syncthreads();
    int n = s_n;

    if (n < kk || n > CAP) {
        // ---- fallback: exact histogram threshold (2 extra row passes) ----
        for (int i = tid; i < HIST_BINS; i += THREADS) s_hist[i] = 0;
        if (tid == 0) { s_n = 0; s_maxkey = 0; }
        __syncthreads();
        for (int i = tid; i < vocab; i += THREADS) {
            float a = row[i] / T;
            unsigned k = orderKey(a);
            atomicAdd(&s_hist[k >> 20], 1);
            atomicMax(&s_maxkey, k);
        }
        __syncthreads();
        if (tid == 0) {
            int B = (int)(s_maxkey >> 20);
            int cum = 0;
            while (true) {
                cum += s_hist[B];
                if (cum >= kk || B == 0) break;
                --B;
            }
            s_T = ((unsigned)B) << 20;
        }
        __syncthreads();
        const unsigned Tkey = s_T;
        for (int i = tid; i < vocab; i += THREADS) {
            float a = row[i] / T;
            if (orderKey(a) >= Tkey) {
                int p = atomicAdd(&s_n, 1);
                if (p < CAP) { s_vals[p] = a; s_idx[p] = i; }
            }
        }
        __syncthreads();
        n = s_n;
        if (n > CAP) n = CAP;
    }

    // ---- rank-sort collected (value desc, original index asc) ----
    for (int i = tid; i < n; i += THREADS) {
        float v = s_vals[i];
        int id = s_idx[i];
        int r = 0;
        for (int j = 0; j < n; ++j) {
            float w = s_vals[j];
            r += (w > v) || (w == v && s_idx[j] < id);
        }
        s_sorted[r] = v;
        if (r == 0) s_amax = id;   // first-index argmax of scaled row
    }
    __syncthreads();

    if (tid == 0) {
        float thr = s_sorted[kk - 1];
        int m = kk;
        while (m < n && s_sorted[m] >= thr) ++m;  // ties at thr_k survive
        s_m = m;
    }
    __syncthreads();
    const int m = s_m;
    const float M = s_sorted[0];
    for (int i = tid; i < m; i += THREADS) s_vals[i] = expf(s_sorted[i] - M);
    __syncthreads();
    if (tid == 0) {
        float Z1 = 0.f;
        for (int i = 0; i < m; ++i) Z1 += s_vals[i];
        const float topp = topp_p[0];
        int j = m - 1;
        float c = 0.f;
        for (int i = 0; i < m; ++i) {
            float p = s_vals[i] / Z1;
            c += p;
            if (c > topp) { j = i; break; }
        }
        float Z2 = 0.f;
        for (int i = 0; i <= j; ++i) Z2 += s_vals[i];
        ws_prob[t] = 1.0f / Z2;
        ws_token[t] = s_amax;
    }
}

// One wave per batch: stable sort by score desc, filter, write int32 outputs.
__global__ __launch_bounds__(64) void finalize_kernel(
    const float* __restrict__ ws_prob,
    const int* __restrict__ ws_token,
    const int* __restrict__ rel_idx,
    const int* __restrict__ boff,
    const int* __restrict__ cu_filtered,
    const int* __restrict__ num_transfer,
    const float* __restrict__ thresholds,
    int bsz, int L,
    int* __restrict__ out)
{
    const int bq = blockIdx.x;
    const int l = threadIdx.x;
    const int start = cu_filtered[bq];
    int cnt = cu_filtered[bq + 1] - start;
    if (cnt > L) cnt = L;

    __shared__ float ss[64]; __shared__ int stk[64]; __shared__ int sp[64];
    __shared__ float ss2[64]; __shared__ int stk2[64]; __shared__ int sp2[64];

    float score = -INFINITY; int tok = 0; int pos = 0;
    if (l < L) {
        if (l < cnt) {
            int t = start + l;
            score = ws_prob[t];
            tok = ws_token[t];
            pos = rel_idx[t] + boff[bq];
        }
        ss[l] = score; stk[l] = tok; sp[l] = pos;
    }
    __syncthreads();
    if (l < L) {
        int r = 0;
        for (int j = 0; j < L; ++j) {
            float w = ss[j];
            r += (w > score) || (w == score && j < l);
        }
        ss2[r] = score; stk2[r] = tok; sp2[r] = pos;
    }
    __syncthreads();

    int k = num_transfer[bq]; if (k < 0) k = 0;
    const float thrb = thresholds[bq];
    bool kp = false;
    if (l < L) {
        float s = ss2[l];
        kp = (l < k) && (s >= thrb) && (s > -INFINITY);
        out[bq * L + l] = kp ? sp2[l] : 0;
        out[bsz * L + bq * L + l] = kp ? stk2[l] : -1;
    }
    unsigned long long mask = __ballot(kp);
    if (l == 0) out[2 * bsz * L + bq] = (int)__popcll(mask);
}

extern "C" void kernel_launch(void* const* d_in, const int* in_sizes, int n_in,
                              void* d_out, int out_size, void* d_ws, size_t ws_size,
                              hipStream_t stream) {
    const float* logits   = (const float*)d_in[0];
    const int*   rel      = (const int*)d_in[1];
    const int*   boff     = (const int*)d_in[2];
    const int*   cuf      = (const int*)d_in[3];
    const int*   cuq      = (const int*)d_in[4];
    const float* temps    = (const float*)d_in[5];
    const int*   ntr      = (const int*)d_in[6];
    const float* thr      = (const float*)d_in[7];
    const float* topp     = (const float*)d_in[8];
    const int*   topk     = (const int*)d_in[9];

    const int total = in_sizes[1];
    const int bsz   = in_sizes[6];
    const long long logits_n = (long long)in_sizes[0];
    const int L = (out_size - bsz) / (2 * bsz);   // block_size

    float* ws_prob = (float*)d_ws;
    int*   ws_tok  = (int*)(ws_prob + total);

    token_kernel<<<total, THREADS, 0, stream>>>(
        logits, rel, cuf, cuq, temps, topk, topp, bsz, logits_n, ws_prob, ws_tok);

    finalize_kernel<<<bsz, 64, 0, stream>>>(
        ws_prob, ws_tok, rel, boff, cuf, ntr, thr, bsz, L, (int*)d_out);
}

// Round 4
// 76.783 us; speedup vs baseline: 1.6926x; 1.3264x over previous
//
#include <hip/hip_runtime.h>
#include <math.h>

#define THREADS 256
#define CAP 512
#define HIST_BINS 4096
#define RAW_THRESH 2.5f

__device__ __forceinline__ unsigned orderKey(float f) {
    unsigned u = __float_as_uint(f);
    return (u & 0x80000000u) ? ~u : (u | 0x80000000u);
}

union SmemU {
    struct { float vals[CAP]; int idx[CAP]; float sorted[CAP]; } a;  // 6 KB
    int hist[HIST_BINS];                                             // 16 KB
};

// One block per candidate token. Single streaming pass over the logits row:
// collect (scaled, idx) for raw >= RAW_THRESH (superset of top-kk whenever
// count >= kk, verified at runtime; exact histogram fallback otherwise), then
// exact top-k / top-p / softmax arithmetic on the small collected set.
__global__ __launch_bounds__(THREADS, 8) void token_kernel(
    const float* __restrict__ logits,
    const int* __restrict__ rel_idx,
    const int* __restrict__ cu_filtered,
    const int* __restrict__ cu_q,
    const float* __restrict__ temps,
    const int* __restrict__ topk_p,
    const float* __restrict__ topp_p,
    int bsz, long long logits_n,
    float* __restrict__ ws_prob,
    int* __restrict__ ws_token)
{
    __shared__ SmemU u;
    __shared__ int s_n, s_m, s_amax;
    __shared__ unsigned s_T, s_maxkey;

    const int t = blockIdx.x;
    const int tid = threadIdx.x;

    if (tid == 0) s_n = 0;

    // per-thread binary search for group id (cu_filtered is tiny + cached)
    int lo = 0, hi = bsz;
    while (hi - lo > 1) {
        int mid = (lo + hi) >> 1;
        if (t >= cu_filtered[mid]) lo = mid; else hi = mid;
    }
    const int b = lo;

    const int nrows = cu_q[bsz];
    const int vocab = (int)(logits_n / (long long)nrows);
    int kk = topk_p[0];
    if (kk > vocab) kk = vocab;
    const float T = temps[t];
    const long long grow = (long long)cu_q[b] + (long long)rel_idx[t];
    const float* row = logits + grow * (long long)vocab;
    const float4* row4 = (const float4*)row;
    const int nv4 = vocab >> 2;
    __syncthreads();

    // ---- single streaming pass: collect raw >= RAW_THRESH (2 float4 / iter) ----
    int i = tid;
    for (; i + THREADS < nv4; i += 2 * THREADS) {
        float4 v0 = row4[i];
        float4 v1 = row4[i + THREADS];
        int b0 = i << 2, b1 = (i + THREADS) << 2;
        if (v0.x >= RAW_THRESH) { int p = atomicAdd(&s_n, 1); if (p < CAP) { u.a.vals[p] = v0.x / T; u.a.idx[p] = b0; } }
        if (v0.y >= RAW_THRESH) { int p = atomicAdd(&s_n, 1); if (p < CAP) { u.a.vals[p] = v0.y / T; u.a.idx[p] = b0 + 1; } }
        if (v0.z >= RAW_THRESH) { int p = atomicAdd(&s_n, 1); if (p < CAP) { u.a.vals[p] = v0.z / T; u.a.idx[p] = b0 + 2; } }
        if (v0.w >= RAW_THRESH) { int p = atomicAdd(&s_n, 1); if (p < CAP) { u.a.vals[p] = v0.w / T; u.a.idx[p] = b0 + 3; } }
        if (v1.x >= RAW_THRESH) { int p = atomicAdd(&s_n, 1); if (p < CAP) { u.a.vals[p] = v1.x / T; u.a.idx[p] = b1; } }
        if (v1.y >= RAW_THRESH) { int p = atomicAdd(&s_n, 1); if (p < CAP) { u.a.vals[p] = v1.y / T; u.a.idx[p] = b1 + 1; } }
        if (v1.z >= RAW_THRESH) { int p = atomicAdd(&s_n, 1); if (p < CAP) { u.a.vals[p] = v1.z / T; u.a.idx[p] = b1 + 2; } }
        if (v1.w >= RAW_THRESH) { int p = atomicAdd(&s_n, 1); if (p < CAP) { u.a.vals[p] = v1.w / T; u.a.idx[p] = b1 + 3; } }
    }
    for (; i < nv4; i += THREADS) {
        float4 v = row4[i];
        int base = i << 2;
        if (v.x >= RAW_THRESH) { int p = atomicAdd(&s_n, 1); if (p < CAP) { u.a.vals[p] = v.x / T; u.a.idx[p] = base; } }
        if (v.y >= RAW_THRESH) { int p = atomicAdd(&s_n, 1); if (p < CAP) { u.a.vals[p] = v.y / T; u.a.idx[p] = base + 1; } }
        if (v.z >= RAW_THRESH) { int p = atomicAdd(&s_n, 1); if (p < CAP) { u.a.vals[p] = v.z / T; u.a.idx[p] = base + 2; } }
        if (v.w >= RAW_THRESH) { int p = atomicAdd(&s_n, 1); if (p < CAP) { u.a.vals[p] = v.w / T; u.a.idx[p] = base + 3; } }
    }
    for (int j = (nv4 << 2) + tid; j < vocab; j += THREADS) {
        float v = row[j];
        if (v >= RAW_THRESH) { int p = atomicAdd(&s_n, 1); if (p < CAP) { u.a.vals[p] = v / T; u.a.idx[p] = j; } }
    }
    __syncthreads();
    int n = s_n;

    if (n < kk || n > CAP) {
        // ---- fallback: exact histogram threshold (2 extra row passes) ----
        // hist aliases the collection arrays; they are rebuilt afterwards.
        __syncthreads();
        for (int j = tid; j < HIST_BINS; j += THREADS) u.hist[j] = 0;
        if (tid == 0) { s_n = 0; s_maxkey = 0; }
        __syncthreads();
        for (int j = tid; j < vocab; j += THREADS) {
            float a = row[j] / T;
            unsigned k = orderKey(a);
            atomicAdd(&u.hist[k >> 20], 1);
            atomicMax(&s_maxkey, k);
        }
        __syncthreads();
        if (tid == 0) {
            int B = (int)(s_maxkey >> 20);
            int cum = 0;
            while (true) {
                cum += u.hist[B];
                if (cum >= kk || B == 0) break;
                --B;
            }
            s_T = ((unsigned)B) << 20;
        }
        __syncthreads();
        const unsigned Tkey = s_T;
        for (int j = tid; j < vocab; j += THREADS) {
            float a = row[j] / T;
            if (orderKey(a) >= Tkey) {
                int p = atomicAdd(&s_n, 1);
                if (p < CAP) { u.a.vals[p] = a; u.a.idx[p] = j; }
            }
        }
        __syncthreads();
        n = s_n;
        if (n > CAP) n = CAP;
    }

    // ---- rank-sort collected (value desc, original index asc) ----
    for (int j = tid; j < n; j += THREADS) {
        float v = u.a.vals[j];
        int id = u.a.idx[j];
        int r = 0;
        for (int q = 0; q < n; ++q) {
            float w = u.a.vals[q];
            r += (w > v) || (w == v && u.a.idx[q] < id);
        }
        u.a.sorted[r] = v;
        if (r == 0) s_amax = id;   // first-index argmax of scaled row
    }
    __syncthreads();

    if (tid == 0) {
        float thr = u.a.sorted[kk - 1];
        int m = kk;
        while (m < n && u.a.sorted[m] >= thr) ++m;  // ties at thr_k survive
        s_m = m;
    }
    __syncthreads();
    const int m = s_m;
    const float M = u.a.sorted[0];
    for (int j = tid; j < m; j += THREADS) u.a.vals[j] = expf(u.a.sorted[j] - M);
    __syncthreads();
    if (tid == 0) {
        float Z1 = 0.f;
        for (int j = 0; j < m; ++j) Z1 += u.a.vals[j];
        const float topp = topp_p[0];
        int jcut = m - 1;
        float c = 0.f;
        for (int j = 0; j < m; ++j) {
            float p = u.a.vals[j] / Z1;
            c += p;
            if (c > topp) { jcut = j; break; }
        }
        float Z2 = 0.f;
        for (int j = 0; j <= jcut; ++j) Z2 += u.a.vals[j];
        ws_prob[t] = 1.0f / Z2;
        ws_token[t] = s_amax;
    }
}

// One wave per batch: stable sort by score desc, filter, write int32 outputs.
__global__ __launch_bounds__(64) void finalize_kernel(
    const float* __restrict__ ws_prob,
    const int* __restrict__ ws_token,
    const int* __restrict__ rel_idx,
    const int* __restrict__ boff,
    const int* __restrict__ cu_filtered,
    const int* __restrict__ num_transfer,
    const float* __restrict__ thresholds,
    int bsz, int L,
    int* __restrict__ out)
{
    const int bq = blockIdx.x;
    const int l = threadIdx.x;
    const int start = cu_filtered[bq];
    int cnt = cu_filtered[bq + 1] - start;
    if (cnt > L) cnt = L;

    __shared__ float ss[64]; __shared__ int stk[64]; __shared__ int sp[64];
    __shared__ float ss2[64]; __shared__ int stk2[64]; __shared__ int sp2[64];

    float score = -INFINITY; int tok = 0; int pos = 0;
    if (l < L) {
        if (l < cnt) {
            int t = start + l;
            score = ws_prob[t];
            tok = ws_token[t];
            pos = rel_idx[t] + boff[bq];
        }
        ss[l] = score; stk[l] = tok; sp[l] = pos;
    }
    __syncthreads();
    if (l < L) {
        int r = 0;
        for (int j = 0; j < L; ++j) {
            float w = ss[j];
            r += (w > score) || (w == score && j < l);
        }
        ss2[r] = score; stk2[r] = tok; sp2[r] = pos;
    }
    __syncthreads();

    int k = num_transfer[bq]; if (k < 0) k = 0;
    const float thrb = thresholds[bq];
    bool kp = false;
    if (l < L) {
        float s = ss2[l];
        kp = (l < k) && (s >= thrb) && (s > -INFINITY);
        out[bq * L + l] = kp ? sp2[l] : 0;
        out[bsz * L + bq * L + l] = kp ? stk2[l] : -1;
    }
    unsigned long long mask = __ballot(kp);
    if (l == 0) out[2 * bsz * L + bq] = (int)__popcll(mask);
}

extern "C" void kernel_launch(void* const* d_in, const int* in_sizes, int n_in,
                              void* d_out, int out_size, void* d_ws, size_t ws_size,
                              hipStream_t stream) {
    const float* logits   = (const float*)d_in[0];
    const int*   rel      = (const int*)d_in[1];
    const int*   boff     = (const int*)d_in[2];
    const int*   cuf      = (const int*)d_in[3];
    const int*   cuq      = (const int*)d_in[4];
    const float* temps    = (const float*)d_in[5];
    const int*   ntr      = (const int*)d_in[6];
    const float* thr      = (const float*)d_in[7];
    const float* topp     = (const float*)d_in[8];
    const int*   topk     = (const int*)d_in[9];

    const int total = in_sizes[1];
    const int bsz   = in_sizes[6];
    const long long logits_n = (long long)in_sizes[0];
    const int L = (out_size - bsz) / (2 * bsz);   // block_size

    float* ws_prob = (float*)d_ws;
    int*   ws_tok  = (int*)(ws_prob + total);

    token_kernel<<<total, THREADS, 0, stream>>>(
        logits, rel, cuf, cuq, temps, topk, topp, bsz, logits_n, ws_prob, ws_tok);

    finalize_kernel<<<bsz, 64, 0, stream>>>(
        ws_prob, ws_tok, rel, boff, cuf, ntr, thr, bsz, L, (int*)d_out);
}